// Round 20
// baseline (257.731 us; speedup 1.0000x reference)
//
#include <hip/hip_runtime.h>
#include <hip/hip_bf16.h>
#include <math.h>

#define B 4
#define H 256
#define W 256
#define HW 65536
#define BHW (B * HW)
#define LSTEPS 10
#define NCH 100
#define KS 51
#define KR 25

typedef __fp16 h2 __attribute__((ext_vector_type(2)));
typedef __fp16 half8 __attribute__((ext_vector_type(8)));
typedef float f32x4 __attribute__((ext_vector_type(4)));
typedef unsigned u32x4v __attribute__((ext_vector_type(4)));
typedef unsigned u32x2v __attribute__((ext_vector_type(2)));

static __device__ __forceinline__ h2 pack_f16(float a, float b) {
#if __has_builtin(__builtin_amdgcn_cvt_pkrtz)
    return __builtin_amdgcn_cvt_pkrtz(a, b);
#else
    h2 r; r.x = (__fp16)a; r.y = (__fp16)b; return r;
#endif
}
static __device__ __forceinline__ unsigned packu(float a, float b) {
    return __builtin_bit_cast(unsigned, pack_f16(a, b));
}

// ---------------- init: images[0]/residuals[0], gauss weights, f16 MFMA weight packs
__global__ void init_kernel(const float* __restrict__ src, const float* __restrict__ z0,
                            const float* __restrict__ conv1_w, const float* __restrict__ conv1_b,
                            const float* __restrict__ conv2_w,
                            float* __restrict__ images0, float* __restrict__ res0,
                            unsigned* __restrict__ gwpk,
                            unsigned* __restrict__ a1, unsigned* __restrict__ a2) {
    int tid = blockIdx.x * 256 + threadIdx.x;   // 0 .. BHW-1
    images0[tid] = src[tid];
    res0[tid] = z0[tid & (HW - 1)];
    if (tid == 0) {
        float e[KS];
        float s = 0.f;
        for (int k = 0; k < KS; k++) {
            float x = (float)(k - KR) / 6.0f;
            e[k] = expf(-0.5f * x * x);
            s += e[k];
        }
        for (int k = 0; k < KS; k++) {
            float g = e[k] / s;
            gwpk[k] = packu(g, g);
        }
    }
    if (tid < LSTEPS * 112) {
        int i = tid / 112, c = tid % 112;
        unsigned* dst = a1 + (size_t)tid * 16;
        if (c < NCH) {
            const float* wz = conv1_w + ((size_t)i * NCH + c) * 18;
            float bias = conv1_b[(size_t)i * NCH + c];
#pragma unroll
            for (int t = 0; t < 9; t++) dst[t] = packu(wz[t], wz[9 + t]);
            dst[9] = packu(bias, 0.f);
#pragma unroll
            for (int t = 10; t < 16; t++) dst[t] = 0u;
        } else {
#pragma unroll
            for (int t = 0; t < 16; t++) dst[t] = 0u;
        }
    }
    if (tid >= 4096 && tid < 4096 + LSTEPS * 16) {
        int r = tid - 4096;
        int i = r / 16, q = r % 16;
        unsigned* dst = a2 + (size_t)r * 64;
        for (int cp = 0; cp < 64; cp++) {
            int c0 = 2 * cp, c1 = 2 * cp + 1;
            float f0 = (q < 9 && c0 < NCH) ? conv2_w[((size_t)i * NCH + c0) * 9 + q] : 0.f;
            float f1 = (q < 9 && c1 < NCH) ? conv2_w[((size_t)i * NCH + c1) * 9 + q] : 0.f;
            dst[cp] = packu(f0, f1);
        }
    }
}

// ---------------- K1: MFMA resblock. XCD-aligned bid remap (bid%8 == q8%8).
// feat_l swizzle upgraded to ((x&3)^((x>>2)&3)) — kills the 4-way B1-read conflict.
__global__ __launch_bounds__(256, 4) void mfma_smap_kernel(
        const float* __restrict__ z, const float* __restrict__ img,
        const unsigned* __restrict__ a1, const unsigned* __restrict__ a2,
        __hip_bfloat16* __restrict__ S,
        float* __restrict__ grads_i, unsigned* __restrict__ t01) {
    __shared__ unsigned feat_l[256 * 16];
    __shared__ unsigned h_l[64 * 64];
    __shared__ float zrow[3][W + 2];
    __shared__ float irow[3][W + 2];
    int bid = blockIdx.x;
    int x8 = bid & 7;
    int t8 = bid >> 5;
    int j4 = (bid >> 3) & 3;
    int q8 = t8 * 8 + x8;
    int b = q8 >> 6;
    int y = (((q8 & 63) << 2) | j4);
    int x = threadIdx.x;
    int p = y * W + x;
    const float* zp = z + (b << 16);
    const float* ip = img + (b << 16);

    bool rv0, rv1, rv2;
#pragma unroll
    for (int r = 0; r < 3; r++) {
        int yy = y - 1 + r;
        bool rv = ((unsigned)yy < (unsigned)H);
        int yc = min(max(yy, 0), H - 1);
        zrow[r][x + 1] = rv ? zp[yc * W + x] : 0.f;
        irow[r][x + 1] = ip[yc * W + x];
        if (x == 0) {
            zrow[r][0] = 0.f;       zrow[r][W + 1] = 0.f;
            irow[r][0] = ip[yc * W + 0];
            irow[r][W + 1] = ip[yc * W + (W - 1)];
        }
        if (r == 0) rv0 = rv; else if (r == 1) rv1 = rv; else rv2 = rv;
    }
    __syncthreads();

    float ir[9], zv9[9];
#pragma unroll
    for (int r = 0; r < 3; r++)
#pragma unroll
        for (int c = 0; c < 3; c++) {
            ir[r * 3 + c] = irow[r][x + c];
            zv9[r * 3 + c] = zrow[r][x + c];
        }
    float gx = ((ir[2] + 2.f * ir[5] + ir[8]) - (ir[0] + 2.f * ir[3] + ir[6])) * 0.125f;
    float gy = ((ir[6] + 2.f * ir[7] + ir[8]) - (ir[0] + 2.f * ir[1] + ir[2])) * 0.125f;
    grads_i[(b * 2 + 0) * HW + p] = gx;
    grads_i[(b * 2 + 1) * HW + p] = gy;
    float zc = zv9[4];
    t01[(b << 16) + p] = packu(-zc * gx, -zc * gy);

    unsigned fd[16];
#pragma unroll
    for (int r = 0; r < 3; r++) {
        bool rv = (r == 0) ? rv0 : (r == 1) ? rv1 : rv2;
#pragma unroll
        for (int c = 0; c < 3; c++) {
            int k = r * 3 + c;
            bool ok = rv && ((unsigned)(x + c - 1) < (unsigned)W);
            float iv = ok ? ir[k] : 0.f;
            fd[k] = packu(zv9[k], iv);
        }
    }
    fd[9] = packu(1.0f, 0.f);
#pragma unroll
    for (int k = 10; k < 16; k++) fd[k] = 0u;

    {
        unsigned base = (unsigned)(x * 16);
        unsigned swzf = (unsigned)((((x & 3) ^ ((x >> 2) & 3))) << 2);
#pragma unroll
        for (int g = 0; g < 4; g++) {
            u32x4v v = {fd[g * 4], fd[g * 4 + 1], fd[g * 4 + 2], fd[g * 4 + 3]};
            *(u32x4v*)(feat_l + base + ((unsigned)(g * 4) ^ swzf)) = v;
        }
    }
    if (x < 64) {
        unsigned swz0 = (unsigned)((x & 15) << 2);
        u32x4v zv = {0u, 0u, 0u, 0u};
        *(u32x4v*)(h_l + x * 64 + (56u ^ swz0)) = zv;
        *(u32x4v*)(h_l + x * 64 + (60u ^ swz0)) = zv;
    }

    int w = threadIdx.x >> 6;
    int lane = threadIdx.x & 63;
    int l15 = lane & 15, lg = lane >> 4;

    half8 A1f[7];
#pragma unroll
    for (int mt = 0; mt < 7; mt++)
        A1f[mt] = __builtin_bit_cast(half8,
            *(const u32x4v*)(a1 + (size_t)((mt * 16 + l15) * 16 + lg * 4)));
    half8 A2f[4];
#pragma unroll
    for (int ks = 0; ks < 4; ks++)
        A2f[ks] = __builtin_bit_cast(half8,
            *(const u32x4v*)(a2 + (size_t)(l15 * 64 + ks * 16 + lg * 4)));

    __syncthreads();

    unsigned hrow = (unsigned)((w * 16 + l15) * 64);
    unsigned swz = (unsigned)(l15 << 2);
    unsigned fswz = (unsigned)((((l15 & 3) ^ ((l15 >> 2) & 3))) << 2);
    const h2 c001 = {(__fp16)0.01f, (__fp16)0.01f};

#pragma unroll
    for (int qt = 0; qt < 4; qt++) {
        int pxq = qt * 64 + w * 16;
        half8 B1f = __builtin_bit_cast(half8,
            *(const u32x4v*)(feat_l + (unsigned)((pxq + l15) * 16) + ((unsigned)(lg * 4) ^ fswz)));
        f32x4 zero4 = {0.f, 0.f, 0.f, 0.f};
        f32x4 acc[7];
#pragma unroll
        for (int mt = 0; mt < 7; mt++)
            acc[mt] = __builtin_amdgcn_mfma_f32_16x16x32_f16(A1f[mt], B1f, zero4, 0, 0, 0);
#pragma unroll
        for (int mt = 0; mt < 7; mt++) {
            h2 h01 = pack_f16(acc[mt][0], acc[mt][1]);
            h2 h23 = pack_f16(acc[mt][2], acc[mt][3]);
            h01 = __builtin_elementwise_max(h01, h01 * c001);
            h23 = __builtin_elementwise_max(h23, h23 * c001);
            u32x2v dv = {__builtin_bit_cast(unsigned, h01), __builtin_bit_cast(unsigned, h23)};
            unsigned c = (unsigned)(mt * 8 + lg * 2);
            *(u32x2v*)(h_l + hrow + (c ^ swz)) = dv;
        }
        f32x4 acc2 = {0.f, 0.f, 0.f, 0.f};
#pragma unroll
        for (int ks = 0; ks < 4; ks++) {
            half8 B2f = __builtin_bit_cast(half8,
                *(const u32x4v*)(h_l + hrow + ((unsigned)(ks * 16 + lg * 4) ^ swz)));
            acc2 = __builtin_amdgcn_mfma_f32_16x16x32_f16(A2f[ks], B2f, acc2, 0, 0, 0);
        }
        int xg = pxq + l15;
        size_t sbase = (size_t)(b << 16) + (size_t)y * W + xg;
#pragma unroll
        for (int r = 0; r < 4; r++) {
            int qq = lg * 4 + r;
            if (qq < 9) S[(size_t)qq * BHW + sbase] = __float2bfloat16(acc2[r]);
        }
    }
}

// ---------------- K2: 2-row blocks (512 blocks x 512 threads, 2 blocks/CU),
// LDS row-staged blur + fields + S-gather + deform. XCD-aligned: bid%8 == q8%8
// where q8 is the 4-row producer tile id.
__global__ __launch_bounds__(512, 4) void vhblur_deform_kernel(
        const unsigned* __restrict__ t01g,
        const unsigned* __restrict__ gwpk,
        float* __restrict__ fields_i,
        const float* __restrict__ img, const float* __restrict__ z,
        const __hip_bfloat16* __restrict__ S,
        float* __restrict__ res_next, float* __restrict__ img_next) {
    __shared__ unsigned st[52][W];          // rows y0-25 .. y0+26, zero-padded
    __shared__ unsigned hs[2][W + 2 * KR];
    int bid = blockIdx.x;
    int x8 = bid & 7;
    int k = bid >> 3;              // 0..63
    int q8 = (k >> 1) * 8 + x8;    // producer 4-row tile, XCD q8%8 == bid%8
    int half = k & 1;
    int b = q8 >> 6;
    int y0 = ((q8 & 63) << 2) + half * 2;
    int tid = threadIdx.x;
    int r = tid >> 8;              // 0..1
    int x = tid & 255;
    const unsigned* t01 = t01g + (b << 16);

    // stage 52 rows (coalesced)
    for (int j = r; j < 52; j += 2) {
        int rr = y0 - KR + j;
        st[j][x] = ((unsigned)rr < (unsigned)H) ? t01[rr * W + x] : 0u;
    }
    __syncthreads();

    // vertical blur from LDS
    h2 vacc[3];
#pragma unroll
    for (int j = 0; j < 3; j++) { h2 zz = {(__fp16)0.f, (__fp16)0.f}; vacc[j] = zz; }
#pragma unroll
    for (int kk = 0; kk < KS; kk++) {
        h2 tv = __builtin_bit_cast(h2, st[r + kk][x]);
        h2 wv = __builtin_bit_cast(h2, gwpk[kk]);
        vacc[kk % 3] = wv * tv + vacc[kk % 3];
    }
    h2 v01 = vacc[0] + vacc[1] + vacc[2];
    hs[r][KR + x] = __builtin_bit_cast(unsigned, v01);
    if (x < KR) hs[r][x] = 0u;
    else if (x >= W - KR) hs[r][x + 2 * KR] = 0u;
    __syncthreads();

    // horizontal blur
    h2 hacc[3];
#pragma unroll
    for (int j = 0; j < 3; j++) { h2 zz = {(__fp16)0.f, (__fp16)0.f}; hacc[j] = zz; }
#pragma unroll
    for (int kk = 0; kk < KS; kk++) {
        h2 sv = __builtin_bit_cast(h2, hs[r][x + kk]);
        h2 wv = __builtin_bit_cast(h2, gwpk[kk]);
        hacc[kk % 3] = wv * sv + hacc[kk % 3];
    }
    h2 a01 = hacc[0] + hacc[1] + hacc[2];
    float a0 = (float)a01.x, a1v = (float)a01.y;

    int y = y0 + r;
    int p = y * W + x;
    int gtid = (b << 16) + p;
    float2* fdst = (float2*)(fields_i + (size_t)gtid * 2);
    *fdst = make_float2(a0, a1v);

    // conv2 finish: out[y,x] = sum_q S_q[y-1+qy, x-1+qx], S == 0 outside image
    float f = 0.f;
#pragma unroll
    for (int q = 0; q < 9; q++) {
        int yy = y - 1 + q / 3;
        int xx = x - 1 + q % 3;
        if (((unsigned)yy < (unsigned)H) && ((unsigned)xx < (unsigned)W))
            f += __bfloat162float(S[(size_t)q * BHW + (b << 16) + yy * W + xx]);
    }
    float zn = z[gtid] + f / 10.0f;
    res_next[gtid] = zn;

    // bilinear deform
    float sx = (float)x - a0 / 10.0f;
    float sy = (float)y - a1v / 10.0f;
    float x0f = floorf(sx), y0f = floorf(sy);
    float wx = sx - x0f, wy = sy - y0f;
    int ix0 = min(max((int)x0f, 0), W - 1);
    int ix1 = min(max((int)x0f + 1, 0), W - 1);
    int iy0 = min(max((int)y0f, 0), H - 1);
    int iy1 = min(max((int)y0f + 1, 0), H - 1);
    const float* im = img + (b << 16);
    float Ia = im[iy0 * W + ix0], Ib = im[iy0 * W + ix1];
    float Ic = im[iy1 * W + ix0], Id = im[iy1 * W + ix1];
    float out = (1.f - wx) * (1.f - wy) * Ia + wx * (1.f - wy) * Ib
              + (1.f - wx) * wy * Ic + wx * wy * Id;
    img_next[gtid] = out + zn * 0.001f;
}

extern "C" void kernel_launch(void* const* d_in, const int* in_sizes, int n_in,
                              void* d_out, int out_size, void* d_ws, size_t ws_size,
                              hipStream_t stream) {
    const float* source  = (const float*)d_in[0];
    const float* z0      = (const float*)d_in[1];
    const float* conv1_w = (const float*)d_in[2];
    const float* conv1_b = (const float*)d_in[3];
    const float* conv2_w = (const float*)d_in[4];

    float* out = (float*)d_out;
    float* images    = out;                              // [11][B][HW]
    float* fields    = images + (size_t)11 * B * HW;     // [10][B][HW][2]
    float* residuals = fields + (size_t)10 * B * HW * 2; // [11][B][HW]
    float* grads     = residuals + (size_t)11 * B * HW;  // [10][B][2][HW]

    unsigned* t01 = (unsigned*)d_ws;                     // [B][HW] packed (tx,ty) f16
    __hip_bfloat16* S = (__hip_bfloat16*)(t01 + (size_t)BHW);        // [9][BHW] bf16
    unsigned* gwpk = (unsigned*)(S + (size_t)9 * BHW);               // [64]
    unsigned* a1 = gwpk + 64;                 // [10][112][16] dw
    unsigned* a2 = a1 + (size_t)LSTEPS * 112 * 16;  // [10][16][64] dw

    init_kernel<<<BHW / 256, 256, 0, stream>>>(source, z0, conv1_w, conv1_b, conv2_w,
                                               images, residuals, gwpk, a1, a2);

    for (int i = 0; i < LSTEPS; i++) {
        const float* img_i = images + (size_t)i * B * HW;
        const float* z_i   = residuals + (size_t)i * B * HW;
        float* fields_i    = fields + (size_t)i * B * HW * 2;

        mfma_smap_kernel<<<B * H, 256, 0, stream>>>(z_i, img_i,
                a1 + (size_t)i * 112 * 16, a2 + (size_t)i * 16 * 64, S,
                grads + (size_t)i * B * 2 * HW, t01);
        vhblur_deform_kernel<<<B * H / 2, 512, 0, stream>>>(t01, gwpk, fields_i,
                img_i, z_i, S,
                residuals + (size_t)(i + 1) * B * HW, images + (size_t)(i + 1) * B * HW);
    }
}

// Round 21
// 228.372 us; speedup vs baseline: 1.1286x; 1.1286x over previous
//
#include <hip/hip_runtime.h>
#include <hip/hip_bf16.h>
#include <math.h>

#define B 4
#define H 256
#define W 256
#define HW 65536
#define BHW (B * HW)
#define LSTEPS 10
#define NCH 100
#define KS 51
#define KR 25

typedef __fp16 h2 __attribute__((ext_vector_type(2)));
typedef __fp16 half8 __attribute__((ext_vector_type(8)));
typedef float f32x4 __attribute__((ext_vector_type(4)));
typedef unsigned u32x4v __attribute__((ext_vector_type(4)));
typedef unsigned u32x2v __attribute__((ext_vector_type(2)));

static __device__ __forceinline__ h2 pack_f16(float a, float b) {
#if __has_builtin(__builtin_amdgcn_cvt_pkrtz)
    return __builtin_amdgcn_cvt_pkrtz(a, b);
#else
    h2 r; r.x = (__fp16)a; r.y = (__fp16)b; return r;
#endif
}
static __device__ __forceinline__ unsigned packu(float a, float b) {
    return __builtin_bit_cast(unsigned, pack_f16(a, b));
}

// ---------------- init: images[0]/residuals[0], gauss weights, f16 MFMA weight packs
__global__ void init_kernel(const float* __restrict__ src, const float* __restrict__ z0,
                            const float* __restrict__ conv1_w, const float* __restrict__ conv1_b,
                            const float* __restrict__ conv2_w,
                            float* __restrict__ images0, float* __restrict__ res0,
                            unsigned* __restrict__ gwpk,
                            unsigned* __restrict__ a1, unsigned* __restrict__ a2) {
    int tid = blockIdx.x * 256 + threadIdx.x;   // 0 .. BHW-1
    images0[tid] = src[tid];
    res0[tid] = z0[tid & (HW - 1)];
    if (tid == 0) {
        float e[KS];
        float s = 0.f;
        for (int k = 0; k < KS; k++) {
            float x = (float)(k - KR) / 6.0f;
            e[k] = expf(-0.5f * x * x);
            s += e[k];
        }
        for (int k = 0; k < KS; k++) {
            float g = e[k] / s;
            gwpk[k] = packu(g, g);
        }
    }
    if (tid < LSTEPS * 112) {
        int i = tid / 112, c = tid % 112;
        unsigned* dst = a1 + (size_t)tid * 16;
        if (c < NCH) {
            const float* wz = conv1_w + ((size_t)i * NCH + c) * 18;
            float bias = conv1_b[(size_t)i * NCH + c];
#pragma unroll
            for (int t = 0; t < 9; t++) dst[t] = packu(wz[t], wz[9 + t]);
            dst[9] = packu(bias, 0.f);
#pragma unroll
            for (int t = 10; t < 16; t++) dst[t] = 0u;
        } else {
#pragma unroll
            for (int t = 0; t < 16; t++) dst[t] = 0u;
        }
    }
    if (tid >= 4096 && tid < 4096 + LSTEPS * 16) {
        int r = tid - 4096;
        int i = r / 16, q = r % 16;
        unsigned* dst = a2 + (size_t)r * 64;
        for (int cp = 0; cp < 64; cp++) {
            int c0 = 2 * cp, c1 = 2 * cp + 1;
            float f0 = (q < 9 && c0 < NCH) ? conv2_w[((size_t)i * NCH + c0) * 9 + q] : 0.f;
            float f1 = (q < 9 && c1 < NCH) ? conv2_w[((size_t)i * NCH + c1) * 9 + q] : 0.f;
            dst[cp] = packu(f0, f1);
        }
    }
}

// ---------------- K1: MFMA resblock. XCD-aligned bid remap (bid%8 == q8%8).
// feat_l swizzle ((x&3)^((x>>2)&3)) — kills the 4-way B1-read bank conflict.
__global__ __launch_bounds__(256, 4) void mfma_smap_kernel(
        const float* __restrict__ z, const float* __restrict__ img,
        const unsigned* __restrict__ a1, const unsigned* __restrict__ a2,
        __hip_bfloat16* __restrict__ S,
        float* __restrict__ grads_i, unsigned* __restrict__ t01) {
    __shared__ unsigned feat_l[256 * 16];
    __shared__ unsigned h_l[64 * 64];
    __shared__ float zrow[3][W + 2];
    __shared__ float irow[3][W + 2];
    int bid = blockIdx.x;
    int x8 = bid & 7;
    int t8 = bid >> 5;
    int j4 = (bid >> 3) & 3;
    int q8 = t8 * 8 + x8;
    int b = q8 >> 6;
    int y = (((q8 & 63) << 2) | j4);
    int x = threadIdx.x;
    int p = y * W + x;
    const float* zp = z + (b << 16);
    const float* ip = img + (b << 16);

    bool rv0, rv1, rv2;
#pragma unroll
    for (int r = 0; r < 3; r++) {
        int yy = y - 1 + r;
        bool rv = ((unsigned)yy < (unsigned)H);
        int yc = min(max(yy, 0), H - 1);
        zrow[r][x + 1] = rv ? zp[yc * W + x] : 0.f;
        irow[r][x + 1] = ip[yc * W + x];
        if (x == 0) {
            zrow[r][0] = 0.f;       zrow[r][W + 1] = 0.f;
            irow[r][0] = ip[yc * W + 0];
            irow[r][W + 1] = ip[yc * W + (W - 1)];
        }
        if (r == 0) rv0 = rv; else if (r == 1) rv1 = rv; else rv2 = rv;
    }
    __syncthreads();

    float ir[9], zv9[9];
#pragma unroll
    for (int r = 0; r < 3; r++)
#pragma unroll
        for (int c = 0; c < 3; c++) {
            ir[r * 3 + c] = irow[r][x + c];
            zv9[r * 3 + c] = zrow[r][x + c];
        }
    float gx = ((ir[2] + 2.f * ir[5] + ir[8]) - (ir[0] + 2.f * ir[3] + ir[6])) * 0.125f;
    float gy = ((ir[6] + 2.f * ir[7] + ir[8]) - (ir[0] + 2.f * ir[1] + ir[2])) * 0.125f;
    grads_i[(b * 2 + 0) * HW + p] = gx;
    grads_i[(b * 2 + 1) * HW + p] = gy;
    float zc = zv9[4];
    t01[(b << 16) + p] = packu(-zc * gx, -zc * gy);

    unsigned fd[16];
#pragma unroll
    for (int r = 0; r < 3; r++) {
        bool rv = (r == 0) ? rv0 : (r == 1) ? rv1 : rv2;
#pragma unroll
        for (int c = 0; c < 3; c++) {
            int k = r * 3 + c;
            bool ok = rv && ((unsigned)(x + c - 1) < (unsigned)W);
            float iv = ok ? ir[k] : 0.f;
            fd[k] = packu(zv9[k], iv);
        }
    }
    fd[9] = packu(1.0f, 0.f);
#pragma unroll
    for (int k = 10; k < 16; k++) fd[k] = 0u;

    {
        unsigned base = (unsigned)(x * 16);
        unsigned swzf = (unsigned)((((x & 3) ^ ((x >> 2) & 3))) << 2);
#pragma unroll
        for (int g = 0; g < 4; g++) {
            u32x4v v = {fd[g * 4], fd[g * 4 + 1], fd[g * 4 + 2], fd[g * 4 + 3]};
            *(u32x4v*)(feat_l + base + ((unsigned)(g * 4) ^ swzf)) = v;
        }
    }
    if (x < 64) {
        unsigned swz0 = (unsigned)((x & 15) << 2);
        u32x4v zv = {0u, 0u, 0u, 0u};
        *(u32x4v*)(h_l + x * 64 + (56u ^ swz0)) = zv;
        *(u32x4v*)(h_l + x * 64 + (60u ^ swz0)) = zv;
    }

    int w = threadIdx.x >> 6;
    int lane = threadIdx.x & 63;
    int l15 = lane & 15, lg = lane >> 4;

    half8 A1f[7];
#pragma unroll
    for (int mt = 0; mt < 7; mt++)
        A1f[mt] = __builtin_bit_cast(half8,
            *(const u32x4v*)(a1 + (size_t)((mt * 16 + l15) * 16 + lg * 4)));
    half8 A2f[4];
#pragma unroll
    for (int ks = 0; ks < 4; ks++)
        A2f[ks] = __builtin_bit_cast(half8,
            *(const u32x4v*)(a2 + (size_t)(l15 * 64 + ks * 16 + lg * 4)));

    __syncthreads();

    unsigned hrow = (unsigned)((w * 16 + l15) * 64);
    unsigned swz = (unsigned)(l15 << 2);
    unsigned fswz = (unsigned)((((l15 & 3) ^ ((l15 >> 2) & 3))) << 2);
    const h2 c001 = {(__fp16)0.01f, (__fp16)0.01f};

#pragma unroll
    for (int qt = 0; qt < 4; qt++) {
        int pxq = qt * 64 + w * 16;
        half8 B1f = __builtin_bit_cast(half8,
            *(const u32x4v*)(feat_l + (unsigned)((pxq + l15) * 16) + ((unsigned)(lg * 4) ^ fswz)));
        f32x4 zero4 = {0.f, 0.f, 0.f, 0.f};
        f32x4 acc[7];
#pragma unroll
        for (int mt = 0; mt < 7; mt++)
            acc[mt] = __builtin_amdgcn_mfma_f32_16x16x32_f16(A1f[mt], B1f, zero4, 0, 0, 0);
#pragma unroll
        for (int mt = 0; mt < 7; mt++) {
            h2 h01 = pack_f16(acc[mt][0], acc[mt][1]);
            h2 h23 = pack_f16(acc[mt][2], acc[mt][3]);
            h01 = __builtin_elementwise_max(h01, h01 * c001);
            h23 = __builtin_elementwise_max(h23, h23 * c001);
            u32x2v dv = {__builtin_bit_cast(unsigned, h01), __builtin_bit_cast(unsigned, h23)};
            unsigned c = (unsigned)(mt * 8 + lg * 2);
            *(u32x2v*)(h_l + hrow + (c ^ swz)) = dv;
        }
        f32x4 acc2 = {0.f, 0.f, 0.f, 0.f};
#pragma unroll
        for (int ks = 0; ks < 4; ks++) {
            half8 B2f = __builtin_bit_cast(half8,
                *(const u32x4v*)(h_l + hrow + ((unsigned)(ks * 16 + lg * 4) ^ swz)));
            acc2 = __builtin_amdgcn_mfma_f32_16x16x32_f16(A2f[ks], B2f, acc2, 0, 0, 0);
        }
        int xg = pxq + l15;
        size_t sbase = (size_t)(b << 16) + (size_t)y * W + xg;
#pragma unroll
        for (int r = 0; r < 4; r++) {
            int qq = lg * 4 + r;
            if (qq < 9) S[(size_t)qq * BHW + sbase] = __float2bfloat16(acc2[r]);
        }
    }
}

// ---------------- K2: 4-row blocks, LDS row-staged blur + fields + S-gather + deform
// (exact round-18 shape: 256 blocks x 1024 threads)
__global__ __launch_bounds__(1024, 1) void vhblur_deform_kernel(
        const unsigned* __restrict__ t01g,
        const unsigned* __restrict__ gwpk,
        float* __restrict__ fields_i,
        const float* __restrict__ img, const float* __restrict__ z,
        const __hip_bfloat16* __restrict__ S,
        float* __restrict__ res_next, float* __restrict__ img_next) {
    __shared__ unsigned st[54][W];
    __shared__ unsigned hs[4][W + 2 * KR];
    int bid = blockIdx.x;
    int b = bid >> 6;
    int y0 = (bid & 63) << 2;
    int tid = threadIdx.x;
    int r = tid >> 8;
    int x = tid & 255;
    const unsigned* t01 = t01g + (b << 16);

    for (int j = r; j < 54; j += 4) {
        int rr = y0 - KR + j;
        st[j][x] = ((unsigned)rr < (unsigned)H) ? t01[rr * W + x] : 0u;
    }
    __syncthreads();

    h2 vacc[3];
#pragma unroll
    for (int j = 0; j < 3; j++) { h2 zz = {(__fp16)0.f, (__fp16)0.f}; vacc[j] = zz; }
#pragma unroll
    for (int k = 0; k < KS; k++) {
        h2 tv = __builtin_bit_cast(h2, st[r + k][x]);
        h2 wv = __builtin_bit_cast(h2, gwpk[k]);
        vacc[k % 3] = wv * tv + vacc[k % 3];
    }
    h2 v01 = vacc[0] + vacc[1] + vacc[2];
    hs[r][KR + x] = __builtin_bit_cast(unsigned, v01);
    if (x < KR) hs[r][x] = 0u;
    else if (x >= W - KR) hs[r][x + 2 * KR] = 0u;
    __syncthreads();

    h2 hacc[3];
#pragma unroll
    for (int j = 0; j < 3; j++) { h2 zz = {(__fp16)0.f, (__fp16)0.f}; hacc[j] = zz; }
#pragma unroll
    for (int k = 0; k < KS; k++) {
        h2 sv = __builtin_bit_cast(h2, hs[r][x + k]);
        h2 wv = __builtin_bit_cast(h2, gwpk[k]);
        hacc[k % 3] = wv * sv + hacc[k % 3];
    }
    h2 a01 = hacc[0] + hacc[1] + hacc[2];
    float a0 = (float)a01.x, a1v = (float)a01.y;

    int y = y0 + r;
    int p = y * W + x;
    int gtid = (b << 16) + p;
    float2* fdst = (float2*)(fields_i + (size_t)gtid * 2);
    *fdst = make_float2(a0, a1v);

    float f = 0.f;
#pragma unroll
    for (int q = 0; q < 9; q++) {
        int yy = y - 1 + q / 3;
        int xx = x - 1 + q % 3;
        if (((unsigned)yy < (unsigned)H) && ((unsigned)xx < (unsigned)W))
            f += __bfloat162float(S[(size_t)q * BHW + (b << 16) + yy * W + xx]);
    }
    float zn = z[gtid] + f / 10.0f;
    res_next[gtid] = zn;

    float sx = (float)x - a0 / 10.0f;
    float sy = (float)y - a1v / 10.0f;
    float x0f = floorf(sx), y0f = floorf(sy);
    float wx = sx - x0f, wy = sy - y0f;
    int ix0 = min(max((int)x0f, 0), W - 1);
    int ix1 = min(max((int)x0f + 1, 0), W - 1);
    int iy0 = min(max((int)y0f, 0), H - 1);
    int iy1 = min(max((int)y0f + 1, 0), H - 1);
    const float* im = img + (b << 16);
    float Ia = im[iy0 * W + ix0], Ib = im[iy0 * W + ix1];
    float Ic = im[iy1 * W + ix0], Id = im[iy1 * W + ix1];
    float out = (1.f - wx) * (1.f - wy) * Ia + wx * (1.f - wy) * Ib
              + (1.f - wx) * wy * Ic + wx * wy * Id;
    img_next[gtid] = out + zn * 0.001f;
}

extern "C" void kernel_launch(void* const* d_in, const int* in_sizes, int n_in,
                              void* d_out, int out_size, void* d_ws, size_t ws_size,
                              hipStream_t stream) {
    const float* source  = (const float*)d_in[0];
    const float* z0      = (const float*)d_in[1];
    const float* conv1_w = (const float*)d_in[2];
    const float* conv1_b = (const float*)d_in[3];
    const float* conv2_w = (const float*)d_in[4];

    float* out = (float*)d_out;
    float* images    = out;                              // [11][B][HW]
    float* fields    = images + (size_t)11 * B * HW;     // [10][B][HW][2]
    float* residuals = fields + (size_t)10 * B * HW * 2; // [11][B][HW]
    float* grads     = residuals + (size_t)11 * B * HW;  // [10][B][2][HW]

    unsigned* t01 = (unsigned*)d_ws;                     // [B][HW] packed (tx,ty) f16
    __hip_bfloat16* S = (__hip_bfloat16*)(t01 + (size_t)BHW);        // [9][BHW] bf16
    unsigned* gwpk = (unsigned*)(S + (size_t)9 * BHW);               // [64]
    unsigned* a1 = gwpk + 64;                 // [10][112][16] dw
    unsigned* a2 = a1 + (size_t)LSTEPS * 112 * 16;  // [10][16][64] dw

    init_kernel<<<BHW / 256, 256, 0, stream>>>(source, z0, conv1_w, conv1_b, conv2_w,
                                               images, residuals, gwpk, a1, a2);

    for (int i = 0; i < LSTEPS; i++) {
        const float* img_i = images + (size_t)i * B * HW;
        const float* z_i   = residuals + (size_t)i * B * HW;
        float* fields_i    = fields + (size_t)i * B * HW * 2;

        mfma_smap_kernel<<<B * H, 256, 0, stream>>>(z_i, img_i,
                a1 + (size_t)i * 112 * 16, a2 + (size_t)i * 16 * 64, S,
                grads + (size_t)i * B * 2 * HW, t01);
        vhblur_deform_kernel<<<B * H / 4, 1024, 0, stream>>>(t01, gwpk, fields_i,
                img_i, z_i, S,
                residuals + (size_t)(i + 1) * B * HW, images + (size_t)(i + 1) * B * HW);
    }
}